// Round 13
// baseline (50.920 us; speedup 1.0000x reference)
//
#include <hip/hip_runtime.h>
#include <hip/hip_bf16.h>

// y = upsample_nearest_2x2x2(conv1x1(x,W,b)); conv on small grid via bf16 MFMA, replicate 8x.
// x: [2][320][16][32][32] f32, W: [160][320] f32, b: [160] f32 -> out: [2][160][32][64][64] f32
//
// v13 = v9 (38.7us, best) with ONE change: wave tile = 2 s-subtiles x 5 o-tiles
// (was 1 x 10). Fragment ds_reads per chunk per wave: 11 -> 7 (2 bfrag + 5 afrag),
// and each afrag feeds 2 MFMAs. Staging, barrier scheme, prefetch placement, and
// store pattern identical to v9.

#define CI     320
#define CO     160
#define S_IN   16384      // 16*32*32
#define KC     32         // K chunk = one MFMA K-step
#define NT     64         // spatial tile per block
#define NCHUNK (CI / KC)  // 10
#define MTW    5          // M-tiles per wave (80 o)

typedef __attribute__((ext_vector_type(8))) short short8;
typedef __attribute__((ext_vector_type(4))) float f32x4;

static __device__ __forceinline__ unsigned short f2bf(float f) {
    __hip_bfloat16 h = __float2bfloat16(f);   // RNE
    unsigned short u;
    __builtin_memcpy(&u, &h, 2);
    return u;
}
static __device__ __forceinline__ unsigned int pack2(float lo, float hi) {
    return (unsigned int)f2bf(lo) | ((unsigned int)f2bf(hi) << 16);
}

__global__ __launch_bounds__(256) void fused_upconv_v13(
    const float* __restrict__ x,
    const float* __restrict__ Wm,
    const float* __restrict__ bias,
    float* __restrict__ out)
{
    // proven 80B-row layout, x2 buffers (35.8 KB total) — identical to v9
    __shared__ unsigned int XsU[2][NT][20];   // [buf][s][k/2]
    __shared__ unsigned int WsU[2][CO][20];   // [buf][o][k/2]

    const int t      = threadIdx.x;
    const int tile   = blockIdx.x;          // 0..255
    const int b      = blockIdx.y;          // 0..1
    const int s_base = tile * NT;
    const float* xb  = x + (size_t)b * CI * S_IN;

    // ---- staging maps (identical to v9) ----
    const int kp = t >> 4;              // k-pair 0..15
    const int s4 = (t & 15) * 4;        // s-quad base
    const int ow = t >> 3;              // W o-base 0..31
    const int kq = t & 7;               // W k-quad 0..7

    float4 xr0, xr1;
    float4 wr[5];

    // prefetch chunk 0
    {
        xr0 = *(const float4*)&xb[(size_t)(2 * kp)     * S_IN + s_base + s4];
        xr1 = *(const float4*)&xb[(size_t)(2 * kp + 1) * S_IN + s_base + s4];
        #pragma unroll
        for (int it = 0; it < 5; ++it)
            wr[it] = *(const float4*)&Wm[(size_t)(ow + it * 32) * CI + kq * 4];
    }

    // ---- fragment indices: wave = (s-half32, o-half80) ----
    const int lane = t & 63;
    const int wid  = t >> 6;
    const int sh2  = wid & 1;           // s-half: subtiles {sh2*32 .. sh2*32+31}
    const int oh   = wid >> 1;          // o-half: 80 o's
    const int frow = lane & 15;
    const int fk   = lane >> 4;
    const int o_base = oh * 80;

    f32x4 acc[MTW][2];
    #pragma unroll
    for (int m = 0; m < MTW; ++m) {
        acc[m][0] = (f32x4){0.f, 0.f, 0.f, 0.f};
        acc[m][1] = (f32x4){0.f, 0.f, 0.f, 0.f};
    }

    for (int c = 0; c < NCHUNK; ++c) {
        const int bs = c & 1;

        // stage regs -> LDS buf[bs] (identical to v9)
        {
            float xa[4] = {xr0.x, xr0.y, xr0.z, xr0.w};
            float xc[4] = {xr1.x, xr1.y, xr1.z, xr1.w};
            #pragma unroll
            for (int j = 0; j < 4; ++j)
                XsU[bs][s4 + j][kp] = pack2(xa[j], xc[j]);   // k=2kp low, 2kp+1 high
            #pragma unroll
            for (int it = 0; it < 5; ++it) {
                uint2 p = make_uint2(pack2(wr[it].x, wr[it].y), pack2(wr[it].z, wr[it].w));
                *(uint2*)&WsU[bs][ow + it * 32][kq * 2] = p;
            }
        }
        __syncthreads();   // single barrier: publishes buf[bs]; vmcnt drained by pack2

        // prefetch chunk c+1 AFTER the barrier (identical to v9)
        if (c < NCHUNK - 1) {
            const int kc = (c + 1) * KC;
            xr0 = *(const float4*)&xb[(size_t)(kc + 2 * kp)     * S_IN + s_base + s4];
            xr1 = *(const float4*)&xb[(size_t)(kc + 2 * kp + 1) * S_IN + s_base + s4];
            #pragma unroll
            for (int it = 0; it < 5; ++it)
                wr[it] = *(const float4*)&Wm[(size_t)(ow + it * 32) * CI + kc + kq * 4];
        }

        // compute chunk c from buf[bs]: 2 bfrag + 5 afrag reads, 10 MFMAs
        const short8 bf0 =
            *(const short8*)((const char*)(&XsU[bs][sh2 * 32 + frow][0]) + fk * 16);
        const short8 bf1 =
            *(const short8*)((const char*)(&XsU[bs][sh2 * 32 + 16 + frow][0]) + fk * 16);
        #pragma unroll
        for (int m = 0; m < MTW; ++m) {
            const short8 af =
                *(const short8*)((const char*)(&WsU[bs][o_base + m * 16 + frow][0]) + fk * 16);
            acc[m][0] = __builtin_amdgcn_mfma_f32_16x16x32_bf16(af, bf0, acc[m][0], 0, 0, 0);
            acc[m][1] = __builtin_amdgcn_mfma_f32_16x16x32_bf16(af, bf1, acc[m][1], 0, 0, 0);
        }
        // race-free per v9's argument: buf reuse at c+2 guarded by barrier c+1.
    }

    // ---- epilogue: same store pattern as v9, per (m, u) sub-tile ----
    const int odd = lane & 1;

    #pragma unroll
    for (int u = 0; u < 2; ++u) {
        const int s   = s_base + sh2 * 32 + u * 16 + frow;   // D col = s
        const int dd  = s >> 10;
        const int hh  = (s >> 5) & 31;
        const int wc0 = (s & 31) & ~1;
        #pragma unroll
        for (int m = 0; m < MTW; ++m) {
            #pragma unroll
            for (int j = 0; j < 4; ++j) {
                const int o = o_base + m * 16 + fk * 4 + j;  // D row = o
                float v  = acc[m][u][j] + bias[o];
                float vp = __shfl_xor(v, 1);
                float lo = odd ? vp : v;
                float hi = odd ? v : vp;
                float4 q = make_float4(lo, lo, hi, hi);
                const size_t base = (((size_t)(b * CO + o) * 32) + (size_t)(2 * dd + odd)) * 4096
                                  + (size_t)(2 * hh) * 64 + (size_t)(2 * wc0);
                *(float4*)&out[base]      = q;
                *(float4*)&out[base + 64] = q;
            }
        }
    }
}

extern "C" void kernel_launch(void* const* d_in, const int* in_sizes, int n_in,
                              void* d_out, int out_size, void* d_ws, size_t ws_size,
                              hipStream_t stream) {
    const float* x    = (const float*)d_in[0];
    const float* Wm   = (const float*)d_in[1];
    const float* bias = (const float*)d_in[2];
    float* out        = (float*)d_out;

    dim3 grid(S_IN / NT, 2);   // (256, 2) = 512 blocks
    dim3 block(256);
    fused_upconv_v13<<<grid, block, 0, stream>>>(x, Wm, bias, out);
}

// Round 14
// 38.685 us; speedup vs baseline: 1.3163x; 1.3163x over previous
//
#include <hip/hip_runtime.h>
#include <hip/hip_bf16.h>

// y = upsample_nearest_2x2x2(conv1x1(x,W,b)); conv on small grid via bf16 MFMA, replicate 8x.
// x: [2][320][16][32][32] f32, W: [160][320] f32, b: [160] f32 -> out: [2][160][32][64][64] f32
//
// v14 = v9 verbatim (best: 38.7us, round 9). Single barrier per K-chunk via
// double-buffered LDS; prefetch issued after the barrier; shfl-pair float4 stores.
// Six restructures (occupancy split, store-streaming, counted-vmcnt pipelines,
// two-pass overlap, wave-tile remap) all regressed -> this is the keeper.

#define CI     320
#define CO     160
#define S_IN   16384      // 16*32*32
#define KC     32         // K chunk = one MFMA K-step
#define NT     64         // spatial tile per block
#define NCHUNK (CI / KC)  // 10
#define MT     (CO / 16)  // 10 M-tiles

typedef __attribute__((ext_vector_type(8))) short short8;
typedef __attribute__((ext_vector_type(4))) float f32x4;

static __device__ __forceinline__ unsigned short f2bf(float f) {
    __hip_bfloat16 h = __float2bfloat16(f);   // RNE
    unsigned short u;
    __builtin_memcpy(&u, &h, 2);
    return u;
}
static __device__ __forceinline__ unsigned int pack2(float lo, float hi) {
    return (unsigned int)f2bf(lo) | ((unsigned int)f2bf(hi) << 16);
}

__global__ __launch_bounds__(256) void fused_upconv_v14(
    const float* __restrict__ x,
    const float* __restrict__ Wm,
    const float* __restrict__ bias,
    float* __restrict__ out)
{
    // bf16 tiles, rows padded to 80 B (20 u32) — proven layout, x2 buffers
    __shared__ unsigned int XsU[2][NT][20];   // [buf][s][k/2]  10 KB
    __shared__ unsigned int WsU[2][CO][20];   // [buf][o][k/2]  25 KB

    const int t      = threadIdx.x;
    const int tile   = blockIdx.x;          // 0..255
    const int b      = blockIdx.y;          // 0..1
    const int s_base = tile * NT;
    const float* xb  = x + (size_t)b * CI * S_IN;

    // ---- staging maps ----
    const int kp = t >> 4;              // k-pair 0..15
    const int s4 = (t & 15) * 4;        // s-quad base
    const int ow = t >> 3;              // W o-base 0..31
    const int kq = t & 7;               // W k-quad 0..7

    float4 xr0, xr1;
    float4 wr[5];

    // prefetch chunk 0
    {
        xr0 = *(const float4*)&xb[(size_t)(2 * kp)     * S_IN + s_base + s4];
        xr1 = *(const float4*)&xb[(size_t)(2 * kp + 1) * S_IN + s_base + s4];
        #pragma unroll
        for (int it = 0; it < 5; ++it)
            wr[it] = *(const float4*)&Wm[(size_t)(ow + it * 32) * CI + kq * 4];
    }

    // ---- fragment indices ----
    const int lane = t & 63;
    const int wid  = t >> 6;        // wave -> 16-s subtile
    const int frow = lane & 15;
    const int fk   = lane >> 4;

    f32x4 acc[MT];
    #pragma unroll
    for (int mt = 0; mt < MT; ++mt) acc[mt] = (f32x4){0.f, 0.f, 0.f, 0.f};

    for (int c = 0; c < NCHUNK; ++c) {
        const int bs = c & 1;

        // stage regs -> LDS buf[bs] (pack2 consumes the loads -> vmcnt drained here)
        {
            float xa[4] = {xr0.x, xr0.y, xr0.z, xr0.w};
            float xc[4] = {xr1.x, xr1.y, xr1.z, xr1.w};
            #pragma unroll
            for (int j = 0; j < 4; ++j)
                XsU[bs][s4 + j][kp] = pack2(xa[j], xc[j]);   // k=2kp low, 2kp+1 high
            #pragma unroll
            for (int it = 0; it < 5; ++it) {
                uint2 p = make_uint2(pack2(wr[it].x, wr[it].y), pack2(wr[it].z, wr[it].w));
                *(uint2*)&WsU[bs][ow + it * 32][kq * 2] = p;
            }
        }
        __syncthreads();   // single barrier: publishes buf[bs]; vmcnt already drained

        // issue prefetch of chunk c+1 AFTER the barrier (overlaps MFMA below)
        if (c < NCHUNK - 1) {
            const int kc = (c + 1) * KC;
            xr0 = *(const float4*)&xb[(size_t)(kc + 2 * kp)     * S_IN + s_base + s4];
            xr1 = *(const float4*)&xb[(size_t)(kc + 2 * kp + 1) * S_IN + s_base + s4];
            #pragma unroll
            for (int it = 0; it < 5; ++it)
                wr[it] = *(const float4*)&Wm[(size_t)(ow + it * 32) * CI + kc + kq * 4];
        }

        // compute chunk c from buf[bs]
        const short8 bfrag =
            *(const short8*)((const char*)(&XsU[bs][wid * 16 + frow][0]) + fk * 16);
        #pragma unroll
        for (int mt = 0; mt < MT; ++mt) {
            const short8 afrag =
                *(const short8*)((const char*)(&WsU[bs][mt * 16 + frow][0]) + fk * 16);
            acc[mt] = __builtin_amdgcn_mfma_f32_16x16x32_bf16(afrag, bfrag, acc[mt], 0, 0, 0);
        }
        // buf[bs] is rewritten at c+2, reachable only after all waves pass barrier
        // c+1, which follows their chunk-c reads -> race-free without 2nd barrier.
    }

    // ---- epilogue: bias + replicate 8x; shfl-pair -> full float4 stores ----
    const int s   = s_base + wid * 16 + frow;   // D col = s
    const int dd  = s >> 10;
    const int hh  = (s >> 5) & 31;
    const int wc  = s & 31;
    const int odd = lane & 1;
    const int wc0 = wc & ~1;

    #pragma unroll
    for (int mt = 0; mt < MT; ++mt) {
        #pragma unroll
        for (int j = 0; j < 4; ++j) {
            const int o = mt * 16 + fk * 4 + j; // D row = o
            float v  = acc[mt][j] + bias[o];
            float vp = __shfl_xor(v, 1);
            float lo = odd ? vp : v;
            float hi = odd ? v : vp;
            float4 q = make_float4(lo, lo, hi, hi);
            const size_t base = (((size_t)(b * CO + o) * 32) + (size_t)(2 * dd + odd)) * 4096
                              + (size_t)(2 * hh) * 64 + (size_t)(2 * wc0);
            *(float4*)&out[base]      = q;
            *(float4*)&out[base + 64] = q;
        }
    }
}

extern "C" void kernel_launch(void* const* d_in, const int* in_sizes, int n_in,
                              void* d_out, int out_size, void* d_ws, size_t ws_size,
                              hipStream_t stream) {
    const float* x    = (const float*)d_in[0];
    const float* Wm   = (const float*)d_in[1];
    const float* bias = (const float*)d_in[2];
    float* out        = (float*)d_out;

    dim3 grid(S_IN / NT, 2);   // (256, 2) = 512 blocks
    dim3 block(256);
    fused_upconv_v14<<<grid, block, 0, stream>>>(x, Wm, bias, out);
}